// Round 1
// baseline (14078.345 us; speedup 1.0000x reference)
//
#include <hip/hip_runtime.h>

// ============================================================================
// UnidirecLSTMLayerWithDropoutBefore: dropout(Threefry) -> x@Wi GEMM -> LSTM scan
// B=64, T=2048, D=256, H=256, gates order (i,f,g,o), dropout rate 0.1, key 42.
//
// ws layout (bytes):
//   [0, 67108864)                      Xd   bf16 [131072][256]   (dropped x)
//   [67108864, 335544320)              Xp   bf16 [2048][64][1024] (x@Wi + b)
//   [335544320, 336068608)             WiT  bf16 [1024][256]     (Wi^T)
//   [336068608, 336592896)             WhP  bf16 packed MFMA B-fragment order
// Output: d_out f32 = c_last[64*256] | h_last[64*256] | outputs[64*2048*256]
// ============================================================================

typedef __attribute__((ext_vector_type(8))) short short8;
typedef __attribute__((ext_vector_type(4))) float floatx4;
typedef __attribute__((ext_vector_type(4))) unsigned short us4;

__device__ __forceinline__ unsigned short f2bf(float f) {
  unsigned int u = __float_as_uint(f);
  u = u + 0x7fffu + ((u >> 16) & 1u);   // RNE
  return (unsigned short)(u >> 16);
}
__device__ __forceinline__ float bf2f(unsigned short s) {
  return __uint_as_float(((unsigned int)s) << 16);
}
__device__ __forceinline__ float fexp2(float x) { return __builtin_amdgcn_exp2f(x); }
__device__ __forceinline__ float frcp(float x) { return __builtin_amdgcn_rcpf(x); }

// ---------------------------------------------------------------------------
// Threefry-2x32, key = (0, 42)  (jax.random.key(42))
// Partitionable scheme (modern JAX default): bits[n] = o0 ^ o1 of TF((0,42),(0,n))
// ---------------------------------------------------------------------------
__device__ __forceinline__ unsigned int tf_bits(unsigned int x0, unsigned int x1) {
  const unsigned int K0 = 0u, K1 = 42u;
  const unsigned int KX = K0 ^ K1 ^ 0x1BD11BDAu;
  x0 += K0; x1 += K1;
#define TF_R(r) { x0 += x1; x1 = (x1 << (r)) | (x1 >> (32 - (r))); x1 ^= x0; }
  TF_R(13) TF_R(15) TF_R(26) TF_R(6)   x0 += K1; x1 += KX + 1u;
  TF_R(17) TF_R(29) TF_R(16) TF_R(24)  x0 += KX; x1 += K0 + 2u;
  TF_R(13) TF_R(15) TF_R(26) TF_R(6)   x0 += K0; x1 += K1 + 3u;
  TF_R(17) TF_R(29) TF_R(16) TF_R(24)  x0 += K1; x1 += KX + 4u;
  TF_R(13) TF_R(15) TF_R(26) TF_R(6)   x0 += KX; x1 += K0 + 5u;
#undef TF_R
  return x0 ^ x1;
}

// K1: dropout + bf16 cast. 4 elems/thread. N = 33554432.
__global__ __launch_bounds__(256) void k_dropout(const float* __restrict__ x,
                                                 unsigned short* __restrict__ xd) {
  const unsigned int base = (blockIdx.x * 256u + threadIdx.x) * 4u;
  const float4 xv = *reinterpret_cast<const float4*>(x + base);
  const float xs[4] = {xv.x, xv.y, xv.z, xv.w};
  us4 o;
#pragma unroll
  for (int j = 0; j < 4; ++j) {
    const unsigned int bits = tf_bits(0u, base + (unsigned int)j);
    const float u = __uint_as_float((bits >> 9) | 0x3f800000u) - 1.0f;
    const float v = (u < 0.9f) ? (xs[j] / 0.9f) : 0.0f;
    o[j] = f2bf(v);
  }
  *reinterpret_cast<us4*>(xd + base) = o;
}

// K0a: WiT[n][k] = bf16(Wi[k][n])
__global__ __launch_bounds__(256) void k_pack_wi(const float* __restrict__ wi,
                                                 unsigned short* __restrict__ wit) {
  const int tid = blockIdx.x * 256 + threadIdx.x;  // 0..262143
  const int n = tid >> 8, k = tid & 255;
  wit[n * 256 + k] = f2bf(wi[k * 1024 + n]);
}

// K0b: WhP packed in MFMA-B fragment order:
//   whp[((nt*8+kt)*64 + lane)*8 + j] = bf16(Wh[kt*32 + (lane>>4)*8 + j][nt*16 + (lane&15)])
__global__ __launch_bounds__(256) void k_pack_wh(const float* __restrict__ wh,
                                                 unsigned short* __restrict__ whp) {
  const int tid = blockIdx.x * 256 + threadIdx.x;  // 0..262143
  const int j = tid & 7, l = (tid >> 3) & 63, kt = (tid >> 9) & 7, nt = tid >> 12;
  const int k = kt * 32 + ((l >> 4) << 3) + j;
  const int n = nt * 16 + (l & 15);
  whp[tid] = f2bf(wh[k * 1024 + n]);
}

// ---------------------------------------------------------------------------
// K2: Xp[t][b][n] = bf16( Xd[b*2048+t][:] @ Wi[:][n] + bias[n] )
// 128x128 tile, BK=32, 4 waves (2x2), reg-staged double-buffered LDS.
// ---------------------------------------------------------------------------
__global__ __launch_bounds__(256) void k_gemm_x(const unsigned short* __restrict__ xd,
                                                const unsigned short* __restrict__ wit,
                                                const float* __restrict__ bias,
                                                unsigned short* __restrict__ xp) {
  __shared__ unsigned short As[2][128 * 40];  // padded row = 40 elems (bank-conflict-free)
  __shared__ unsigned short Bs[2][128 * 40];
  const int tid = threadIdx.x;
  const int lane = tid & 63;
  const int wv = tid >> 6;
  const int wm = wv >> 1, wn = wv & 1;
  const int m0 = blockIdx.x * 128, n0 = blockIdx.y * 128;

  const int srow = tid >> 1, sseg = tid & 1;
  const unsigned short* gA = xd + (m0 + srow) * 256 + sseg * 16;
  const unsigned short* gB = wit + (n0 + srow) * 256 + sseg * 16;
  const int soff = srow * 40 + sseg * 16;

  const floatx4 zero4 = {0.f, 0.f, 0.f, 0.f};
  floatx4 acc[4][4];
#pragma unroll
  for (int i = 0; i < 4; ++i)
#pragma unroll
    for (int j = 0; j < 4; ++j) acc[i][j] = zero4;

  short8 ra0 = *(const short8*)(gA);
  short8 ra1 = *(const short8*)(gA + 8);
  short8 rb0 = *(const short8*)(gB);
  short8 rb1 = *(const short8*)(gB + 8);
  *(short8*)&As[0][soff] = ra0;
  *(short8*)&As[0][soff + 8] = ra1;
  *(short8*)&Bs[0][soff] = rb0;
  *(short8*)&Bs[0][soff + 8] = rb1;
  __syncthreads();

  const int frow = (lane & 15) * 40 + ((lane >> 4) << 3);
#pragma unroll 1
  for (int kt = 0; kt < 8; ++kt) {
    const int buf = kt & 1;
    if (kt < 7) {
      ra0 = *(const short8*)(gA + (kt + 1) * 32);
      ra1 = *(const short8*)(gA + (kt + 1) * 32 + 8);
      rb0 = *(const short8*)(gB + (kt + 1) * 32);
      rb1 = *(const short8*)(gB + (kt + 1) * 32 + 8);
    }
    short8 af[4], bfv[4];
#pragma unroll
    for (int mt = 0; mt < 4; ++mt)
      af[mt] = *(const short8*)&As[buf][(wm * 64 + mt * 16) * 40 + frow];
#pragma unroll
    for (int nt = 0; nt < 4; ++nt)
      bfv[nt] = *(const short8*)&Bs[buf][(wn * 64 + nt * 16) * 40 + frow];
#pragma unroll
    for (int mt = 0; mt < 4; ++mt)
#pragma unroll
      for (int nt = 0; nt < 4; ++nt)
        acc[mt][nt] = __builtin_amdgcn_mfma_f32_16x16x32_bf16(af[mt], bfv[nt], acc[mt][nt], 0, 0, 0);
    if (kt < 7) {
      *(short8*)&As[buf ^ 1][soff] = ra0;
      *(short8*)&As[buf ^ 1][soff + 8] = ra1;
      *(short8*)&Bs[buf ^ 1][soff] = rb0;
      *(short8*)&Bs[buf ^ 1][soff + 8] = rb1;
    }
    __syncthreads();
  }

  // epilogue: C[row=(lane>>4)*4+q][col=lane&15]; Xp layout [t][b][1024]
#pragma unroll
  for (int nt = 0; nt < 4; ++nt) {
    const int gn = n0 + wn * 64 + nt * 16 + (lane & 15);
    const float bv = bias[gn];
#pragma unroll
    for (int mt = 0; mt < 4; ++mt) {
      const int mrow = m0 + wm * 64 + mt * 16 + ((lane >> 4) << 2);
#pragma unroll
      for (int q = 0; q < 4; ++q) {
        const int m = mrow + q;
        const int b = m >> 11, t = m & 2047;
        xp[(size_t)(t * 64 + b) * 1024 + gn] = f2bf(acc[mt][nt][q] + bv);
      }
    }
  }
}

// ---------------------------------------------------------------------------
// K3: persistent LSTM scan. 8 WGs x 8 batch rows, 512 thr (8 waves).
// Wave v owns H-cols [v*32, v*32+32); gate n-tiles ntg = gate*16 + 2v + s.
// h (bf16) lives in LDS (A-operand, M=16 padded, rows 8..15 zero);
// c (f32) lives in VGPRs. Wh streams from L2 in packed fragment order.
// ---------------------------------------------------------------------------
#define LROW 264  // 256 + 8 pad: row stride 528B -> conflict-free b128 frag reads

__global__ __launch_bounds__(512) void k_lstm(const unsigned short* __restrict__ xp,
                                              const unsigned short* __restrict__ whp,
                                              const int* __restrict__ lens,
                                              float* __restrict__ out) {
  __shared__ unsigned short As[2][16 * LROW];
  __shared__ unsigned short Xs[2][8 * 1024];

  const int tid = threadIdx.x;
  const int lane = tid & 63;
  const int wv = tid >> 6;
  const int b0 = blockIdx.x * 8;

  for (int i = tid; i < 16 * LROW; i += 512) { As[0][i] = 0; As[1][i] = 0; }

  // post-redistribution cell geometry: 4 cells/lane: rows rb+q, col hcol
  const int rb = ((lane >> 4) & 1) * 4;
  const int hcol = wv * 32 + (lane >> 5) * 16 + (lane & 15);

  int len_m1[4];
#pragma unroll
  for (int q = 0; q < 4; ++q) len_m1[q] = lens[b0 + rb + q] - 1;

  float c[4] = {0.f, 0.f, 0.f, 0.f};

  // B-fragment base pointers + permanent kt=0 frags
  const unsigned short* wb[8];
  short8 bp0[8];
#pragma unroll
  for (int a = 0; a < 8; ++a) {
    const int ntg = (a >> 1) * 16 + wv * 2 + (a & 1);
    wb[a] = whp + (size_t)ntg * 4096 + lane * 8;
    bp0[a] = *(const short8*)(wb[a]);
  }

  {  // stage Xs[0] for t=0
    const unsigned short* src = xp + (size_t)b0 * 1024 + tid * 16;
    short8 r0 = *(const short8*)src;
    short8 r1 = *(const short8*)(src + 8);
    *(short8*)&Xs[0][tid * 16] = r0;
    *(short8*)&Xs[0][tid * 16 + 8] = r1;
  }
  __syncthreads();

  const floatx4 zero4 = {0.f, 0.f, 0.f, 0.f};
  int cur = 0;

#pragma unroll 1
  for (int t = 0; t < 2048; ++t) {
    short8 bbA[8], bbB[8];
#define BLOAD(DST, KT)                                                      \
  _Pragma("unroll") for (int a = 0; a < 8; ++a)                             \
      DST[a] = *(const short8*)(wb[a] + (KT) * 512);
#define MFMA8(AF, BARR)                                                     \
  _Pragma("unroll") for (int a = 0; a < 8; ++a)                             \
      acc[a] = __builtin_amdgcn_mfma_f32_16x16x32_bf16(AF, BARR[a], acc[a], 0, 0, 0);

    BLOAD(bbA, 1)

    short8 af[8];
#pragma unroll
    for (int kt = 0; kt < 8; ++kt)
      af[kt] = *(const short8*)&As[cur][(lane & 15) * LROW + kt * 32 + ((lane >> 4) << 3)];

    // prefetch next step's Xproj slice (written to LDS at end of iter)
    const int tn = (t + 1) & 2047;
    const unsigned short* xsrc = xp + ((size_t)tn * 64 + b0) * 1024 + tid * 16;
    short8 xr0 = *(const short8*)xsrc;
    short8 xr1 = *(const short8*)(xsrc + 8);

    floatx4 acc[8];
#pragma unroll
    for (int a = 0; a < 8; ++a) acc[a] = zero4;

    MFMA8(af[0], bp0)
    BLOAD(bbB, 2)
    MFMA8(af[1], bbA)
    BLOAD(bbA, 3)
    MFMA8(af[2], bbB)
    BLOAD(bbB, 4)
    MFMA8(af[3], bbA)
    BLOAD(bbA, 5)
    MFMA8(af[4], bbB)
    BLOAD(bbB, 6)
    MFMA8(af[5], bbA)
    BLOAD(bbA, 7)
    MFMA8(af[6], bbB)
    MFMA8(af[7], bbA)
#undef BLOAD
#undef MFMA8

    // gates: redistribute s=1 tiles to lanes 32..63 (full-lane transcendentals)
#pragma unroll
    for (int q = 0; q < 4; ++q) {
      const int row = rb + q;
      float z[4];
#pragma unroll
      for (int g = 0; g < 4; ++g) {
        const float own = acc[g * 2 + 0][q];
        const float oth = __shfl_xor(acc[g * 2 + 1][q], 32, 64);
        const float zsel = (lane < 32) ? own : oth;
        z[g] = zsel + bf2f(Xs[cur][row * 1024 + g * 256 + hcol]);
      }
      const float zi = fminf(fmaxf(z[0], -20.f), 20.f);
      const float zf = fminf(fmaxf(z[1], -20.f), 20.f);
      const float zg = fminf(fmaxf(z[2], -20.f), 20.f);
      const float zo = fminf(fmaxf(z[3], -20.f), 20.f);
      // sigmoid(i)*tanh(g) = e^i (e^{2g}-1) / ((e^i+1)(e^{2g}+1))
      const float ei = fexp2(zi * 1.44269504f);
      const float e2g = fexp2(zg * 2.88539008f);
      const float p1 = ei * (e2g - 1.f) * frcp((ei + 1.f) * (e2g + 1.f));
      const float ef = fexp2(-zf * 1.44269504f);
      const float cn = frcp(1.f + ef) * c[q] + p1;
      c[q] = cn;
      const float cc = fminf(fmaxf(cn, -15.f), 15.f);
      const float eo = fexp2(zo * 1.44269504f);
      const float e2c = fexp2(cc * 2.88539008f);
      const float h = eo * (e2c - 1.f) * frcp((eo + 1.f) * (e2c + 1.f));

      As[cur ^ 1][row * LROW + hcol] = f2bf(h);
      out[32768 + ((size_t)(b0 + row) * 2048 + t) * 256 + hcol] = h;
      if (t == len_m1[q]) {
        out[(b0 + row) * 256 + hcol] = cn;
        out[16384 + (b0 + row) * 256 + hcol] = h;
      }
    }

    *(short8*)&Xs[cur ^ 1][tid * 16] = xr0;
    *(short8*)&Xs[cur ^ 1][tid * 16 + 8] = xr1;
    __syncthreads();
    cur ^= 1;
  }
}

// ---------------------------------------------------------------------------
extern "C" void kernel_launch(void* const* d_in, const int* in_sizes, int n_in,
                              void* d_out, int out_size, void* d_ws, size_t ws_size,
                              hipStream_t stream) {
  (void)in_sizes; (void)n_in; (void)out_size; (void)ws_size;
  const float* x = (const float*)d_in[0];
  const float* wi = (const float*)d_in[1];
  const float* wh = (const float*)d_in[2];
  const float* bias = (const float*)d_in[3];
  const int* lens = (const int*)d_in[4];
  float* out = (float*)d_out;

  char* ws = (char*)d_ws;
  unsigned short* xd = (unsigned short*)ws;                               // 64 MiB
  unsigned short* xp = (unsigned short*)(ws + 67108864ull);               // 256 MiB
  unsigned short* wit = (unsigned short*)(ws + 335544320ull);             // 0.5 MiB
  unsigned short* whp = (unsigned short*)(ws + 336068608ull);             // 0.5 MiB

  k_pack_wi<<<1024, 256, 0, stream>>>(wi, wit);
  k_pack_wh<<<1024, 256, 0, stream>>>(wh, whp);
  k_dropout<<<32768, 256, 0, stream>>>(x, xd);
  k_gemm_x<<<dim3(1024, 8), 256, 0, stream>>>(xd, wit, bias, xp);
  k_lstm<<<8, 512, 0, stream>>>(xp, whp, lens, out);
}

// Round 2
// 3725.394 us; speedup vs baseline: 3.7790x; 3.7790x over previous
//
#include <hip/hip_runtime.h>

// ============================================================================
// UnidirecLSTMLayerWithDropoutBefore: dropout(Threefry) -> x@Wi GEMM -> LSTM
// B=64, T=2048, D=256, H=256, gates (i,f,g,o), dropout 0.1, key 42.
//
// R1: weight-RESIDENT recurrence. Wh quantized to i8 (per-column scale),
// held entirely in VGPRs (128/lane across 8 waves). mfma_i32_16x16x64_i8
// (K=64 -> 256 MFMA/step/CU). h carried as i8 A-fragments in 4KB LDS.
// Zero per-step weight traffic; Xproj prefetched 1 step ahead.
//
// ws layout (bytes):
//   [0, 64MiB)            Xd   bf16 [131072][256]
//   [64MiB, 320MiB)       Xp2  bf16 [2048][8 grp][8 row][256 u][4 gate]
//   [335544320, +512KiB)  WiT  bf16 [1024][256]
//   [336068608, +4KiB)    dq   f32 [1024]   (s_w/127^2)
//   [336072704, +4KiB)    qs   f32 [1024]   (127/s_w)
//   [336076800, +256KiB)  Wq   i8  packed MFMA-B frags [ntg][kt][lane][16]
// Output f32: c_last[16384] | h_last[16384] | outputs[64*2048*256]
// ============================================================================

typedef __attribute__((ext_vector_type(8))) short short8;
typedef __attribute__((ext_vector_type(4))) float floatx4;
typedef __attribute__((ext_vector_type(4))) int int4v;
typedef __attribute__((ext_vector_type(4))) unsigned short us4;

__device__ __forceinline__ unsigned short f2bf(float f) {
  unsigned int u = __float_as_uint(f);
  u = u + 0x7fffu + ((u >> 16) & 1u);   // RNE
  return (unsigned short)(u >> 16);
}
__device__ __forceinline__ float bf2f(unsigned short s) {
  return __uint_as_float(((unsigned int)s) << 16);
}
__device__ __forceinline__ float fexp2(float x) { return __builtin_amdgcn_exp2f(x); }
__device__ __forceinline__ float frcp(float x) { return __builtin_amdgcn_rcpf(x); }

// ---------------------------------------------------------------------------
// Threefry-2x32, key (0,42), partitionable scheme: bits = o0^o1 of TF((0,42),(0,n))
// (verified bit-exact in R0)
// ---------------------------------------------------------------------------
__device__ __forceinline__ unsigned int tf_bits(unsigned int x0, unsigned int x1) {
  const unsigned int K0 = 0u, K1 = 42u;
  const unsigned int KX = K0 ^ K1 ^ 0x1BD11BDAu;
  x0 += K0; x1 += K1;
#define TF_R(r) { x0 += x1; x1 = (x1 << (r)) | (x1 >> (32 - (r))); x1 ^= x0; }
  TF_R(13) TF_R(15) TF_R(26) TF_R(6)   x0 += K1; x1 += KX + 1u;
  TF_R(17) TF_R(29) TF_R(16) TF_R(24)  x0 += KX; x1 += K0 + 2u;
  TF_R(13) TF_R(15) TF_R(26) TF_R(6)   x0 += K0; x1 += K1 + 3u;
  TF_R(17) TF_R(29) TF_R(16) TF_R(24)  x0 += K1; x1 += KX + 4u;
  TF_R(13) TF_R(15) TF_R(26) TF_R(6)   x0 += KX; x1 += K0 + 5u;
#undef TF_R
  return x0 ^ x1;
}

__global__ __launch_bounds__(256) void k_dropout(const float* __restrict__ x,
                                                 unsigned short* __restrict__ xd) {
  const unsigned int base = (blockIdx.x * 256u + threadIdx.x) * 4u;
  const float4 xv = *reinterpret_cast<const float4*>(x + base);
  const float xs[4] = {xv.x, xv.y, xv.z, xv.w};
  us4 o;
#pragma unroll
  for (int j = 0; j < 4; ++j) {
    const unsigned int bits = tf_bits(0u, base + (unsigned int)j);
    const float u = __uint_as_float((bits >> 9) | 0x3f800000u) - 1.0f;
    const float v = (u < 0.9f) ? (xs[j] / 0.9f) : 0.0f;
    o[j] = f2bf(v);
  }
  *reinterpret_cast<us4*>(xd + base) = o;
}

__global__ __launch_bounds__(256) void k_pack_wi(const float* __restrict__ wi,
                                                 unsigned short* __restrict__ wit) {
  const int tid = blockIdx.x * 256 + threadIdx.x;
  const int n = tid >> 8, k = tid & 255;
  wit[n * 256 + k] = f2bf(wi[k * 1024 + n]);
}

// per-column |max| -> dequant (s/127^2) and quant (127/s) scales
__global__ __launch_bounds__(256) void k_colscale(const float* __restrict__ wh,
                                                  float* __restrict__ dq,
                                                  float* __restrict__ qs) {
  const int n = blockIdx.x * 256 + threadIdx.x;  // 0..1023
  float m = 0.f;
  for (int k = 0; k < 256; ++k) m = fmaxf(m, fabsf(wh[k * 1024 + n]));
  const float s = (m > 0.f) ? m : 1.f;
  dq[n] = s / 16129.0f;
  qs[n] = 127.0f / s;
}

// Wq packed in i8 MFMA-B fragment order (16x16x64):
//   wq[((ntg*4+kt)*64 + l)*16 + j] = q(Wh[kt*64 + (l>>4)*16 + j][ntg*16 + (l&15)])
__global__ __launch_bounds__(256) void k_pack_wh_i8(const float* __restrict__ wh,
                                                    const float* __restrict__ qs,
                                                    signed char* __restrict__ wq) {
  const int tid = blockIdx.x * 256 + threadIdx.x;  // 0..262143
  const int j = tid & 15, l = (tid >> 4) & 63, kt = (tid >> 10) & 3, ntg = tid >> 12;
  const int k = kt * 64 + ((l >> 4) << 4) + j;
  const int n = ntg * 16 + (l & 15);
  float v = rintf(wh[k * 1024 + n] * qs[n]);
  v = fminf(fmaxf(v, -127.f), 127.f);
  wq[tid] = (signed char)(int)v;
}

// ---------------------------------------------------------------------------
// K2: Xp2 = bf16(Xd @ Wi + b), written in [t][grp][row][u][gate] layout.
// ---------------------------------------------------------------------------
__global__ __launch_bounds__(256) void k_gemm_x(const unsigned short* __restrict__ xd,
                                                const unsigned short* __restrict__ wit,
                                                const float* __restrict__ bias,
                                                unsigned short* __restrict__ xp) {
  __shared__ unsigned short As[2][128 * 40];
  __shared__ unsigned short Bs[2][128 * 40];
  const int tid = threadIdx.x;
  const int lane = tid & 63;
  const int wv = tid >> 6;
  const int wm = wv >> 1, wn = wv & 1;
  const int m0 = blockIdx.x * 128, n0 = blockIdx.y * 128;

  const int srow = tid >> 1, sseg = tid & 1;
  const unsigned short* gA = xd + (m0 + srow) * 256 + sseg * 16;
  const unsigned short* gB = wit + (n0 + srow) * 256 + sseg * 16;
  const int soff = srow * 40 + sseg * 16;

  const floatx4 zero4 = {0.f, 0.f, 0.f, 0.f};
  floatx4 acc[4][4];
#pragma unroll
  for (int i = 0; i < 4; ++i)
#pragma unroll
    for (int j = 0; j < 4; ++j) acc[i][j] = zero4;

  short8 ra0 = *(const short8*)(gA);
  short8 ra1 = *(const short8*)(gA + 8);
  short8 rb0 = *(const short8*)(gB);
  short8 rb1 = *(const short8*)(gB + 8);
  *(short8*)&As[0][soff] = ra0;
  *(short8*)&As[0][soff + 8] = ra1;
  *(short8*)&Bs[0][soff] = rb0;
  *(short8*)&Bs[0][soff + 8] = rb1;
  __syncthreads();

  const int frow = (lane & 15) * 40 + ((lane >> 4) << 3);
#pragma unroll 1
  for (int kt = 0; kt < 8; ++kt) {
    const int buf = kt & 1;
    if (kt < 7) {
      ra0 = *(const short8*)(gA + (kt + 1) * 32);
      ra1 = *(const short8*)(gA + (kt + 1) * 32 + 8);
      rb0 = *(const short8*)(gB + (kt + 1) * 32);
      rb1 = *(const short8*)(gB + (kt + 1) * 32 + 8);
    }
    short8 af[4], bfv[4];
#pragma unroll
    for (int mt = 0; mt < 4; ++mt)
      af[mt] = *(const short8*)&As[buf][(wm * 64 + mt * 16) * 40 + frow];
#pragma unroll
    for (int nt = 0; nt < 4; ++nt)
      bfv[nt] = *(const short8*)&Bs[buf][(wn * 64 + nt * 16) * 40 + frow];
#pragma unroll
    for (int mt = 0; mt < 4; ++mt)
#pragma unroll
      for (int nt = 0; nt < 4; ++nt)
        acc[mt][nt] = __builtin_amdgcn_mfma_f32_16x16x32_bf16(af[mt], bfv[nt], acc[mt][nt], 0, 0, 0);
    if (kt < 7) {
      *(short8*)&As[buf ^ 1][soff] = ra0;
      *(short8*)&As[buf ^ 1][soff + 8] = ra1;
      *(short8*)&Bs[buf ^ 1][soff] = rb0;
      *(short8*)&Bs[buf ^ 1][soff + 8] = rb1;
    }
    __syncthreads();
  }

#pragma unroll
  for (int nt = 0; nt < 4; ++nt) {
    const int gn = n0 + wn * 64 + nt * 16 + (lane & 15);
    const float bv = bias[gn];
    const int uu = gn & 255, gg = gn >> 8;
#pragma unroll
    for (int mt = 0; mt < 4; ++mt) {
      const int mrow = m0 + wm * 64 + mt * 16 + ((lane >> 4) << 2);
#pragma unroll
      for (int q = 0; q < 4; ++q) {
        const int m = mrow + q;
        const int b = m >> 11, t = m & 2047;
        xp[(((size_t)t * 8 + (b >> 3)) * 8 + (b & 7)) * 1024 + (size_t)uu * 4 + gg] =
            f2bf(acc[mt][nt][q] + bv);
      }
    }
  }
}

// ---------------------------------------------------------------------------
// K3: weight-resident LSTM scan. 8 WGs x 8 rows, 512 thr (8 waves, 2/SIMD).
// Wave v owns units [v*32, v*32+32): ntg(g,p) = g*16 + v*2 + p, p<2.
// Wq: 32 int4v frags/lane (128 VGPR). h: i8 A-frags in 4KB LDS.
// ---------------------------------------------------------------------------
__global__ __launch_bounds__(512, 2) void k_lstm(const unsigned short* __restrict__ xp,
                                                 const signed char* __restrict__ wq,
                                                 const float* __restrict__ dq,
                                                 const int* __restrict__ lens,
                                                 float* __restrict__ out) {
  __shared__ __align__(16) signed char As[4096];  // [kt<4][a_lane<64][16] i8

  const int tid = threadIdx.x, lane = tid & 63, v = tid >> 6;
  const int bg = blockIdx.x, b0 = bg * 8;

  ((long long*)As)[tid] = 0;  // 512 * 8B = 4KB; rows 8..15 stay zero forever

  // resident weights: 32 frags/lane
  int4v w[4][2][4];
#pragma unroll
  for (int g = 0; g < 4; ++g)
#pragma unroll
    for (int p = 0; p < 2; ++p)
#pragma unroll
      for (int kt = 0; kt < 4; ++kt) {
        const int ntg = g * 16 + v * 2 + p;
        w[g][p][kt] = *(const int4v*)(wq + (size_t)(((ntg * 4 + kt) * 64 + lane)) * 16);
      }

  // cell geometry (post shfl_xor(32) redistribution)
  const int rbase = ((lane >> 4) & 1) * 4;                    // rows rbase..rbase+3
  const int u = v * 32 + (lane >> 5) * 16 + (lane & 15);      // hidden unit

  float dqv[4];
#pragma unroll
  for (int g = 0; g < 4; ++g) dqv[g] = dq[g * 256 + u];
  int lenm[4];
#pragma unroll
  for (int q = 0; q < 4; ++q) lenm[q] = lens[b0 + rbase + q] - 1;
  float c[4] = {0.f, 0.f, 0.f, 0.f};

  // Xproj: us4 per (cell-row, u) = the 4 gate values
  us4 xc[4], xn[4];
#pragma unroll
  for (int q = 0; q < 4; ++q)
    xc[q] = *(const us4*)(xp + ((size_t)bg * 8 + rbase + q) * 1024 + u * 4);

  const int4v zacc = {0, 0, 0, 0};
  __syncthreads();

#pragma unroll 1
  for (int t = 0; t < 2048; ++t) {
    // prefetch next step's Xproj (consumed next iteration)
    const size_t tn = (size_t)((t + 1) & 2047);
#pragma unroll
    for (int q = 0; q < 4; ++q)
      xn[q] = *(const us4*)(xp + ((tn * 8 + bg) * 8 + rbase + q) * 1024 + u * 4);

    int4v acc[4][2];
#pragma unroll
    for (int g = 0; g < 4; ++g) { acc[g][0] = zacc; acc[g][1] = zacc; }

    int4v afc = *(const int4v*)&As[lane * 16];
#pragma unroll
    for (int kt = 0; kt < 4; ++kt) {
      int4v afn = afc;
      if (kt < 3) afn = *(const int4v*)&As[(kt + 1) * 1024 + lane * 16];
#pragma unroll
      for (int g = 0; g < 4; ++g)
#pragma unroll
        for (int p = 0; p < 2; ++p)
          acc[g][p] = __builtin_amdgcn_mfma_i32_16x16x64_i8(afc, w[g][p][kt], acc[g][p], 0, 0, 0);
      afc = afn;
    }
    __syncthreads();  // all A-frag reads done before h overwrite

#pragma unroll
    for (int q = 0; q < 4; ++q) {
      const int row = rbase + q;
      float z[4];
#pragma unroll
      for (int g = 0; g < 4; ++g) {
        const int own = acc[g][0][q];
        const int oth = __shfl_xor(acc[g][1][q], 32, 64);
        const int zi = (lane < 32) ? own : oth;
        z[g] = (float)zi * dqv[g] + bf2f(xc[q][g]);
      }
      const float zi_ = fminf(fmaxf(z[0], -20.f), 20.f);
      const float zf_ = fminf(fmaxf(z[1], -20.f), 20.f);
      const float zg_ = fminf(fmaxf(z[2], -20.f), 20.f);
      const float zo_ = fminf(fmaxf(z[3], -20.f), 20.f);
      const float ei = fexp2(zi_ * 1.44269504f);
      const float e2g = fexp2(zg_ * 2.88539008f);
      const float p1 = ei * (e2g - 1.f) * frcp((ei + 1.f) * (e2g + 1.f));
      const float ef = fexp2(-zf_ * 1.44269504f);
      const float cn = frcp(1.f + ef) * c[q] + p1;
      c[q] = cn;
      const float cc = fminf(fmaxf(cn, -15.f), 15.f);
      const float eo = fexp2(zo_ * 1.44269504f);
      const float e2c = fexp2(cc * 2.88539008f);
      const float h = eo * (e2c - 1.f) * frcp((eo + 1.f) * (e2c + 1.f));

      // h -> i8 A-frag slot
      float hq = rintf(h * 127.f);
      hq = fminf(fmaxf(hq, -127.f), 127.f);
      const int ktw = u >> 6;
      const int alane = ((u >> 4) & 3) * 16 + row;
      As[ktw * 1024 + alane * 16 + (u & 15)] = (signed char)(int)hq;

      out[32768 + ((size_t)(b0 + row) * 2048 + t) * 256 + u] = h;
      if (t == lenm[q]) {
        out[(size_t)(b0 + row) * 256 + u] = cn;
        out[16384 + (size_t)(b0 + row) * 256 + u] = h;
      }
    }

#pragma unroll
    for (int q = 0; q < 4; ++q) xc[q] = xn[q];
    __syncthreads();
  }
}

// ---------------------------------------------------------------------------
extern "C" void kernel_launch(void* const* d_in, const int* in_sizes, int n_in,
                              void* d_out, int out_size, void* d_ws, size_t ws_size,
                              hipStream_t stream) {
  (void)in_sizes; (void)n_in; (void)out_size; (void)ws_size;
  const float* x = (const float*)d_in[0];
  const float* wi = (const float*)d_in[1];
  const float* wh = (const float*)d_in[2];
  const float* bias = (const float*)d_in[3];
  const int* lens = (const int*)d_in[4];
  float* out = (float*)d_out;

  char* ws = (char*)d_ws;
  unsigned short* xd = (unsigned short*)ws;                         // 64 MiB
  unsigned short* xp = (unsigned short*)(ws + 67108864ull);         // 256 MiB
  unsigned short* wit = (unsigned short*)(ws + 335544320ull);       // 512 KiB
  float* dq = (float*)(ws + 336068608ull);                          // 4 KiB
  float* qs = (float*)(ws + 336072704ull);                          // 4 KiB
  signed char* wqb = (signed char*)(ws + 336076800ull);             // 256 KiB

  k_pack_wi<<<1024, 256, 0, stream>>>(wi, wit);
  k_colscale<<<4, 256, 0, stream>>>(wh, dq, qs);
  k_pack_wh_i8<<<1024, 256, 0, stream>>>(wh, qs, wqb);
  k_dropout<<<32768, 256, 0, stream>>>(x, xd);
  k_gemm_x<<<dim3(1024, 8), 256, 0, stream>>>(xd, wit, bias, xp);
  k_lstm<<<8, 512, 0, stream>>>(xp, wqb, dq, lens, out);
}

// Round 3
// 1948.738 us; speedup vs baseline: 7.2243x; 1.9117x over previous
//
#include <hip/hip_runtime.h>

// ============================================================================
// UnidirecLSTMLayerWithDropoutBefore: dropout(Threefry) -> x@Wi GEMM -> LSTM
// B=64, T=2048, D=256, H=256, gates (i,f,g,o), dropout 0.1, key 42.
//
// R2: 32 WGs x 2 batch rows (was 8x8) -> 4x less gate VALU per CU, same MFMA.
// Zero-shuffle gate redistribution: h duplicated into A-rows {0,4,8,12} =
// {b0,b1,b0,b1} so acc[g][p][0] lands on the owner lane natively (1 cndmask).
// One barrier/step (double-buffered As), strength-reduced addressing,
// zero-C-in MFMA chains. Weights i8, VGPR-resident (128/lane, validated R1).
//
// ws layout (bytes):
//   [0, 64MiB)            Xd   bf16 [131072][256]
//   [64MiB, 320MiB)       Xp   bf16 [2048][32 wg][2 row][256 u][4 gate]
//   [335544320, +512KiB)  WiT  bf16 [1024][256]
//   [336068608, +4KiB)    dq   f32 [1024]
//   [336072704, +4KiB)    qs   f32 [1024]
//   [336076800, +256KiB)  Wq   i8 packed MFMA-B frags [ntg][kt][lane][16]
// Output f32: c_last[16384] | h_last[16384] | outputs[64*2048*256]
// ============================================================================

typedef __attribute__((ext_vector_type(8))) short short8;
typedef __attribute__((ext_vector_type(4))) float floatx4;
typedef __attribute__((ext_vector_type(4))) int int4v;
typedef __attribute__((ext_vector_type(4))) unsigned short us4;

__device__ __forceinline__ unsigned short f2bf(float f) {
  unsigned int u = __float_as_uint(f);
  u = u + 0x7fffu + ((u >> 16) & 1u);   // RNE
  return (unsigned short)(u >> 16);
}
__device__ __forceinline__ float bf2f(unsigned short s) {
  return __uint_as_float(((unsigned int)s) << 16);
}
__device__ __forceinline__ float fexp2(float x) { return __builtin_amdgcn_exp2f(x); }
__device__ __forceinline__ float frcp(float x) { return __builtin_amdgcn_rcpf(x); }

// ---------------------------------------------------------------------------
// Threefry-2x32, key (0,42), partitionable scheme (verified bit-exact R0/R1)
// ---------------------------------------------------------------------------
__device__ __forceinline__ unsigned int tf_bits(unsigned int x0, unsigned int x1) {
  const unsigned int K0 = 0u, K1 = 42u;
  const unsigned int KX = K0 ^ K1 ^ 0x1BD11BDAu;
  x0 += K0; x1 += K1;
#define TF_R(r) { x0 += x1; x1 = (x1 << (r)) | (x1 >> (32 - (r))); x1 ^= x0; }
  TF_R(13) TF_R(15) TF_R(26) TF_R(6)   x0 += K1; x1 += KX + 1u;
  TF_R(17) TF_R(29) TF_R(16) TF_R(24)  x0 += KX; x1 += K0 + 2u;
  TF_R(13) TF_R(15) TF_R(26) TF_R(6)   x0 += K0; x1 += K1 + 3u;
  TF_R(17) TF_R(29) TF_R(16) TF_R(24)  x0 += K1; x1 += KX + 4u;
  TF_R(13) TF_R(15) TF_R(26) TF_R(6)   x0 += KX; x1 += K0 + 5u;
#undef TF_R
  return x0 ^ x1;
}

__global__ __launch_bounds__(256) void k_dropout(const float* __restrict__ x,
                                                 unsigned short* __restrict__ xd) {
  const unsigned int base = (blockIdx.x * 256u + threadIdx.x) * 4u;
  const float4 xv = *reinterpret_cast<const float4*>(x + base);
  const float xs[4] = {xv.x, xv.y, xv.z, xv.w};
  us4 o;
#pragma unroll
  for (int j = 0; j < 4; ++j) {
    const unsigned int bits = tf_bits(0u, base + (unsigned int)j);
    const float u = __uint_as_float((bits >> 9) | 0x3f800000u) - 1.0f;
    const float v = (u < 0.9f) ? (xs[j] / 0.9f) : 0.0f;
    o[j] = f2bf(v);
  }
  *reinterpret_cast<us4*>(xd + base) = o;
}

__global__ __launch_bounds__(256) void k_pack_wi(const float* __restrict__ wi,
                                                 unsigned short* __restrict__ wit) {
  const int tid = blockIdx.x * 256 + threadIdx.x;
  const int n = tid >> 8, k = tid & 255;
  wit[n * 256 + k] = f2bf(wi[k * 1024 + n]);
}

__global__ __launch_bounds__(256) void k_colscale(const float* __restrict__ wh,
                                                  float* __restrict__ dq,
                                                  float* __restrict__ qs) {
  const int n = blockIdx.x * 256 + threadIdx.x;  // 0..1023
  float m = 0.f;
  for (int k = 0; k < 256; ++k) m = fmaxf(m, fabsf(wh[k * 1024 + n]));
  const float s = (m > 0.f) ? m : 1.f;
  dq[n] = s / 16129.0f;
  qs[n] = 127.0f / s;
}

// Wq packed in i8 MFMA-B fragment order (16x16x64) — layout validated in R1.
__global__ __launch_bounds__(256) void k_pack_wh_i8(const float* __restrict__ wh,
                                                    const float* __restrict__ qs,
                                                    signed char* __restrict__ wq) {
  const int tid = blockIdx.x * 256 + threadIdx.x;  // 0..262143
  const int j = tid & 15, l = (tid >> 4) & 63, kt = (tid >> 10) & 3, ntg = tid >> 12;
  const int k = kt * 64 + ((l >> 4) << 4) + j;
  const int n = ntg * 16 + (l & 15);
  float v = rintf(wh[k * 1024 + n] * qs[n]);
  v = fminf(fmaxf(v, -127.f), 127.f);
  wq[tid] = (signed char)(int)v;
}

// ---------------------------------------------------------------------------
// K2: Xp = bf16(Xd @ Wi + b), layout [t][wg32][row2][u][gate].
// ---------------------------------------------------------------------------
__global__ __launch_bounds__(256) void k_gemm_x(const unsigned short* __restrict__ xd,
                                                const unsigned short* __restrict__ wit,
                                                const float* __restrict__ bias,
                                                unsigned short* __restrict__ xp) {
  __shared__ unsigned short As[2][128 * 40];
  __shared__ unsigned short Bs[2][128 * 40];
  const int tid = threadIdx.x;
  const int lane = tid & 63;
  const int wv = tid >> 6;
  const int wm = wv >> 1, wn = wv & 1;
  const int m0 = blockIdx.x * 128, n0 = blockIdx.y * 128;

  const int srow = tid >> 1, sseg = tid & 1;
  const unsigned short* gA = xd + (m0 + srow) * 256 + sseg * 16;
  const unsigned short* gB = wit + (n0 + srow) * 256 + sseg * 16;
  const int soff = srow * 40 + sseg * 16;

  const floatx4 zero4 = {0.f, 0.f, 0.f, 0.f};
  floatx4 acc[4][4];
#pragma unroll
  for (int i = 0; i < 4; ++i)
#pragma unroll
    for (int j = 0; j < 4; ++j) acc[i][j] = zero4;

  short8 ra0 = *(const short8*)(gA);
  short8 ra1 = *(const short8*)(gA + 8);
  short8 rb0 = *(const short8*)(gB);
  short8 rb1 = *(const short8*)(gB + 8);
  *(short8*)&As[0][soff] = ra0;
  *(short8*)&As[0][soff + 8] = ra1;
  *(short8*)&Bs[0][soff] = rb0;
  *(short8*)&Bs[0][soff + 8] = rb1;
  __syncthreads();

  const int frow = (lane & 15) * 40 + ((lane >> 4) << 3);
#pragma unroll 1
  for (int kt = 0; kt < 8; ++kt) {
    const int buf = kt & 1;
    if (kt < 7) {
      ra0 = *(const short8*)(gA + (kt + 1) * 32);
      ra1 = *(const short8*)(gA + (kt + 1) * 32 + 8);
      rb0 = *(const short8*)(gB + (kt + 1) * 32);
      rb1 = *(const short8*)(gB + (kt + 1) * 32 + 8);
    }
    short8 af[4], bfv[4];
#pragma unroll
    for (int mt = 0; mt < 4; ++mt)
      af[mt] = *(const short8*)&As[buf][(wm * 64 + mt * 16) * 40 + frow];
#pragma unroll
    for (int nt = 0; nt < 4; ++nt)
      bfv[nt] = *(const short8*)&Bs[buf][(wn * 64 + nt * 16) * 40 + frow];
#pragma unroll
    for (int mt = 0; mt < 4; ++mt)
#pragma unroll
      for (int nt = 0; nt < 4; ++nt)
        acc[mt][nt] = __builtin_amdgcn_mfma_f32_16x16x32_bf16(af[mt], bfv[nt], acc[mt][nt], 0, 0, 0);
    if (kt < 7) {
      *(short8*)&As[buf ^ 1][soff] = ra0;
      *(short8*)&As[buf ^ 1][soff + 8] = ra1;
      *(short8*)&Bs[buf ^ 1][soff] = rb0;
      *(short8*)&Bs[buf ^ 1][soff + 8] = rb1;
    }
    __syncthreads();
  }

#pragma unroll
  for (int nt = 0; nt < 4; ++nt) {
    const int gn = n0 + wn * 64 + nt * 16 + (lane & 15);
    const float bv = bias[gn];
    const int uu = gn & 255, gg = gn >> 8;
#pragma unroll
    for (int mt = 0; mt < 4; ++mt) {
      const int mrow = m0 + wm * 64 + mt * 16 + ((lane >> 4) << 2);
#pragma unroll
      for (int q = 0; q < 4; ++q) {
        const int m = mrow + q;
        const int b = m >> 11, t = m & 2047;
        xp[(((size_t)t * 32 + (b >> 1)) * 2 + (b & 1)) * 1024 + (size_t)uu * 4 + gg] =
            f2bf(acc[mt][nt][q] + bv);
      }
    }
  }
}

// ---------------------------------------------------------------------------
// K3: weight-resident LSTM scan. 32 WGs x 2 batch rows, 512 thr (8 waves).
// Wave v owns units [v*32, v*32+32). h duplicated into A-rows {0,4,8,12} =
// {b0,b1,b0,b1}; cell (r,u) lands natively on its lane (q=0, 1 cndmask for p).
// ---------------------------------------------------------------------------
__global__ __launch_bounds__(512, 2) void k_lstm(const unsigned short* __restrict__ xp,
                                                 const signed char* __restrict__ wq,
                                                 const float* __restrict__ dq,
                                                 const int* __restrict__ lens,
                                                 float* __restrict__ out) {
  __shared__ __align__(16) signed char As[8192];  // 2 x [kt<4][alane<64][16] i8

  const int tid = threadIdx.x, lane = tid & 63, v = tid >> 6;
  const int wg = blockIdx.x, b0 = wg * 2;

  const int4v zacc = {0, 0, 0, 0};
  ((int4v*)As)[tid] = zacc;  // 512*16 = 8192: zero both buffers

  // resident weights: 32 frags/lane (128 VGPR)
  int4v w[4][2][4];
#pragma unroll
  for (int g = 0; g < 4; ++g)
#pragma unroll
    for (int p = 0; p < 2; ++p)
#pragma unroll
      for (int kt = 0; kt < 4; ++kt) {
        const int ntg = g * 16 + v * 2 + p;
        w[g][p][kt] = *(const int4v*)(wq + (size_t)(((ntg * 4 + kt) * 64 + lane)) * 16);
      }

  // cell geometry: 1 cell/lane
  const int r = (lane >> 4) & 1;          // batch row within WG
  const int ph = lane >> 5;               // p-half select
  const int u = v * 32 + ph * 16 + (lane & 15);

  float dqv[4];
#pragma unroll
  for (int g = 0; g < 4; ++g) dqv[g] = dq[g * 256 + u];
  const int lenm = lens[b0 + r] - 1;
  float c = 0.f;

  // fixed LDS h-write byte offsets (A-rows r*4 and r*4+8), within one buffer
  const int aw0 = (u >> 6) * 1024 + (((u >> 4) & 3) * 16 + r * 4) * 16 + (u & 15);
  const int aw1 = aw0 + 128;

  // running pointers
  const unsigned short* px = xp + ((size_t)wg * 2 + r) * 1024 + u * 4;
  float* po = out + 32768 + (size_t)(b0 + r) * 2048 * 256 + u;
  float* pc = out + (size_t)(b0 + r) * 256 + u;
  float* ph_last = pc + 16384;

  us4 xc = *(const us4*)px;
  px += 65536;

  __syncthreads();

  int curoff = 0;
  const float LOG2E = 1.44269504f;

#pragma unroll 1
  for (int t = 0; t < 2048; ++t) {
    // prefetch next step's gate slice (t=2047 reads into WiT region: harmless)
    const us4 xn = *(const us4*)px;
    px += 65536;

    // A-fragments from current buffer
    int4v af0 = *(const int4v*)&As[curoff + lane * 16];
    int4v af1 = *(const int4v*)&As[curoff + 1024 + lane * 16];
    int4v af2 = *(const int4v*)&As[curoff + 2048 + lane * 16];
    int4v af3 = *(const int4v*)&As[curoff + 3072 + lane * 16];

    int4v acc[4][2];
#pragma unroll
    for (int g = 0; g < 4; ++g)
#pragma unroll
      for (int p = 0; p < 2; ++p) {
        acc[g][p] = __builtin_amdgcn_mfma_i32_16x16x64_i8(af0, w[g][p][0], zacc, 0, 0, 0);
        acc[g][p] = __builtin_amdgcn_mfma_i32_16x16x64_i8(af1, w[g][p][1], acc[g][p], 0, 0, 0);
        acc[g][p] = __builtin_amdgcn_mfma_i32_16x16x64_i8(af2, w[g][p][2], acc[g][p], 0, 0, 0);
        acc[g][p] = __builtin_amdgcn_mfma_i32_16x16x64_i8(af3, w[g][p][3], acc[g][p], 0, 0, 0);
      }

    // gates: native placement, p-half via cndmask
    float z[4];
#pragma unroll
    for (int g = 0; g < 4; ++g) {
      const int zint = (ph == 0) ? acc[g][0][0] : acc[g][1][0];
      z[g] = fmaf((float)zint, dqv[g], bf2f(xc[g]));
    }
    const float zi_ = fminf(fmaxf(z[0], -20.f), 20.f);
    const float zf_ = fminf(fmaxf(z[1], -20.f), 20.f);
    const float zg_ = fminf(fmaxf(z[2], -20.f), 20.f);
    const float zo_ = fminf(fmaxf(z[3], -20.f), 20.f);
    const float ei = fexp2(zi_ * LOG2E);
    const float e2g = fexp2(zg_ * (2.f * LOG2E));
    const float p1 = ei * (e2g - 1.f) * frcp((ei + 1.f) * (e2g + 1.f));
    const float ef = fexp2(-zf_ * LOG2E);
    const float cn = frcp(1.f + ef) * c + p1;
    c = cn;
    const float cc = fminf(fmaxf(cn, -15.f), 15.f);
    const float eo = fexp2(zo_ * LOG2E);
    const float e2c = fexp2(cc * (2.f * LOG2E));
    const float h = eo * (e2c - 1.f) * frcp((eo + 1.f) * (e2c + 1.f));

    // h -> i8, duplicated A-rows in the other buffer
    float hq = rintf(h * 127.f);
    hq = fminf(fmaxf(hq, -127.f), 127.f);
    const signed char hb = (signed char)(int)hq;
    const int woff = curoff ^ 4096;
    As[woff + aw0] = hb;
    As[woff + aw1] = hb;

    *po = h;
    po += 256;
    if (t == lenm) {
      *pc = cn;
      *ph_last = h;
    }

    xc = xn;
    __syncthreads();
    curoff ^= 4096;
  }
}

// ---------------------------------------------------------------------------
extern "C" void kernel_launch(void* const* d_in, const int* in_sizes, int n_in,
                              void* d_out, int out_size, void* d_ws, size_t ws_size,
                              hipStream_t stream) {
  (void)in_sizes; (void)n_in; (void)out_size; (void)ws_size;
  const float* x = (const float*)d_in[0];
  const float* wi = (const float*)d_in[1];
  const float* wh = (const float*)d_in[2];
  const float* bias = (const float*)d_in[3];
  const int* lens = (const int*)d_in[4];
  float* out = (float*)d_out;

  char* ws = (char*)d_ws;
  unsigned short* xd = (unsigned short*)ws;                         // 64 MiB
  unsigned short* xp = (unsigned short*)(ws + 67108864ull);         // 256 MiB
  unsigned short* wit = (unsigned short*)(ws + 335544320ull);       // 512 KiB
  float* dq = (float*)(ws + 336068608ull);                          // 4 KiB
  float* qs = (float*)(ws + 336072704ull);                          // 4 KiB
  signed char* wqb = (signed char*)(ws + 336076800ull);             // 256 KiB

  k_pack_wi<<<1024, 256, 0, stream>>>(wi, wit);
  k_colscale<<<4, 256, 0, stream>>>(wh, dq, qs);
  k_pack_wh_i8<<<1024, 256, 0, stream>>>(wh, qs, wqb);
  k_dropout<<<32768, 256, 0, stream>>>(x, xd);
  k_gemm_x<<<dim3(1024, 8), 256, 0, stream>>>(xd, wit, bias, xp);
  k_lstm<<<32, 512, 0, stream>>>(xp, wqb, dq, lens, out);
}